// Round 17
// baseline (59.238 us; speedup 1.0000x reference)
//
#include <hip/hip_runtime.h>
#include <math.h>

#ifndef M_PI
#define M_PI 3.14159265358979323846
#endif

#define BATCHES 256
#define S_LEN   131072

// One kernel, independent blocks, truncated-warmup linear recurrence.
// r17: PACKED FP32 (v_pk_fma_f32) -- bands 0,1 as float2 ext-vectors in the
// recurrence (STEP3P: 3 pk + 3 scalar vs 9 scalar FMA-class ops), and
// sample-pair packing in phase 3's correction. Mechanism: timed-window VALU
// busy ~73% (42us of issue cycles in 57.5us) -> VALU issue is the larger of
// the two half-busy pipes; packing cuts static VALU ~25%. All else = r16.
//
// Structure (r12-r16, verified absmax 0.0039): block = 320 thr (5 waves),
// threads 0..255 own 16-sample chunks (4096-sample segment), wave 4 does 48
// warmup chunks (768 samples) concurrently; block-local affine scan (waves
// 0..2, Kogge-Stone over 304 states); phase 3 homogeneous correction
// y(t)=y_zs(t)+c1*H(t)+c2*H(t-1) from LDS; coalesced nt stores; 2 barriers.
#define TPB   320
#define MAINT 256
#define CCH   16
#define SEGS  32                      // segments per row
#define SEG_SAMPS (MAINT * CCH)       // 4096
#define WCH   48                      // warmup chunks (768 samples)
#define NCH   (MAINT + WCH)           // 304 chunks scanned
#define OBSTR 17                      // staging stride (16 samples + 1 pad)
#define SCAN_OFF 4352                 // 256*17 floats of staging
#define SCAN_STR 305                  // per-array scan stride (304 + 1 pad)
#define H_OFF 6184                    // 16B-aligned H table (3 bands x 16)
#define LDSF  6232                    // 24928 B -> 6 blocks/CU (LDS), 30 waves/CU

typedef float v4f __attribute__((ext_vector_type(4)));
typedef float v2f __attribute__((ext_vector_type(2)));

__device__ __forceinline__ void compute_coeffs(float level_in, float b0[3], float na1[3], float na2[3]) {
    const float FD[3] = {270.0f, 800.0f, 2300.0f};
    const float FN[3] = {500.0f, 1500.0f, 2500.0f};
    const float FB[3] = {730.0f, 2100.0f, 3000.0f};
    float level = fminf(fmaxf(level_in, 0.0f), 1.0f);
    float t_low  = fminf(fmaxf(level * 2.0f, 0.0f), 1.0f);
    float t_high = fminf(fmaxf((level - 0.5f) * 2.0f, 0.0f), 1.0f);
    bool hi = (level >= 0.5f);
    const float W0 = (float)(2.0 * M_PI / 16000.0);
    #pragma unroll
    for (int k = 0; k < 3; ++k) {
        float f, q;
        if (hi) { f = (1.0f - t_high) * FN[k] + t_high * FB[k];
                  q = (1.0f - t_high) * 8.0f  + t_high * 12.0f; }
        else    { f = (1.0f - t_low) * FD[k] + t_low * FN[k];
                  q = (1.0f - t_low) * 5.0f  + t_low * 8.0f; }
        float omega = W0 * f;
        float sn = __sinf(omega), cs = __cosf(omega);   // native v_sin/v_cos
        float alpha = sn / (2.0f * fmaxf(q, 0.5f));
        float a0 = 1.0f + alpha;
        b0[k]  = alpha / a0;             // b2 == -b0 exactly
        na1[k] = (2.0f * cs) / a0;       // -a1
        na2[k] = -((1.0f - alpha) / a0); // -a2
    }
}

// Packed biquad step: bands 0,1 in v2f (v_pk_fma_f32), band 2 scalar.
// Uses y1p,y2p (v2f), y1c,y2c (float) and b0p/na1p/na2p/b0c/na1c/na2c from scope.
#define STEP3P(XT, XTM2, SUMV)                                                   \
    {                                                                            \
        float d = (XT) - (XTM2);                                                 \
        v2f dd = {d, d};                                                         \
        v2f ep  = b0p * dd + na2p * y2p;                                         \
        float ec = fmaf(b0c, d, na2c * y2c);                                     \
        v2f yyp = na1p * y1p + ep;                                               \
        float yyc = fmaf(na1c, y1c, ec);                                         \
        y2p = y1p; y1p = yyp;                                                    \
        y2c = y1c; y1c = yyc;                                                    \
        SUMV = yyp.x + yyp.y + yyc;                                              \
    }

// 2x2 matrix multiply: R = X * Y
#define MMUL(R00,R01,R10,R11, X00,X01,X10,X11, Y00,Y01,Y10,Y11)                  \
    {                                                                            \
        R00 = X00*Y00 + X01*Y10; R01 = X00*Y01 + X01*Y11;                        \
        R10 = X10*Y00 + X11*Y10; R11 = X10*Y01 + X11*Y11;                        \
    }

__global__ __launch_bounds__(TPB, 2)
void formant_onepass(const float* __restrict__ x, const float* __restrict__ lvl,
                     float* __restrict__ out)
{
    __shared__ float lds[LDSF];

    const int tid = threadIdx.x;
    const int row = blockIdx.x >> 5;
    const int seg = blockIdx.x & (SEGS - 1);

    float b0[3], na1[3], na2[3];
    compute_coeffs(lvl[row], b0, na1, na2);
    const v2f b0p  = {b0[0],  b0[1]};
    const v2f na1p = {na1[0], na1[1]};
    const v2f na2p = {na2[0], na2[1]};
    const float b0c = b0[2], na1c = na1[2], na2c = na2[2];

    const float* xrow = x + (size_t)row * S_LEN;
    const size_t segBase = (size_t)seg * SEG_SAMPS;

    // -------- phase 1a: main-chunk zero-state (threads 0..255), packed math --------
    if (tid < MAINT) {
        const float* xc = xrow + segBase + (size_t)tid * CCH;
        float xm1 = 0.f, xm2 = 0.f;
        if (seg > 0 || tid > 0) { float2 t2 = *(const float2*)(xc - 2); xm2 = t2.x; xm1 = t2.y; }
        v2f y1p = {0.f,0.f}, y2p = {0.f,0.f};
        float y1c = 0.f, y2c = 0.f;
        const float4* xv = (const float4*)xc;
        float* myob = lds + tid * OBSTR;
        float4 buf[4];
        #pragma unroll
        for (int j = 0; j < 4; ++j) buf[j] = xv[j];
        #pragma unroll
        for (int i = 0; i < 4; ++i) {
            float4 q = buf[i];
            float4 o;
            STEP3P(q.x, xm2, o.x)
            STEP3P(q.y, xm1, o.y)
            STEP3P(q.z, q.x, o.z)
            STEP3P(q.w, q.y, o.w)
            xm2 = q.z; xm1 = q.w;
            // scalar LDS writes: bank=(17*tid + 4i+c)%32 -> exactly 2-way (free)
            myob[4*i + 0] = o.x;
            myob[4*i + 1] = o.y;
            myob[4*i + 2] = o.z;
            myob[4*i + 3] = o.w;
        }
        // end-of-chunk states -> scan arrays at index WCH+tid
        lds[SCAN_OFF + 0*SCAN_STR + WCH + tid] = y1p.x;
        lds[SCAN_OFF + 1*SCAN_STR + WCH + tid] = y2p.x;
        lds[SCAN_OFF + 2*SCAN_STR + WCH + tid] = y1p.y;
        lds[SCAN_OFF + 3*SCAN_STR + WCH + tid] = y2p.y;
        lds[SCAN_OFF + 4*SCAN_STR + WCH + tid] = y1c;
        lds[SCAN_OFF + 5*SCAN_STR + WCH + tid] = y2c;
    }
    // -------- phase 1b: warmup chunks on DEDICATED wave 4 (threads 256..303) --------
    else if (tid < MAINT + WCH) {
        const int wid = tid - MAINT;
        if (seg == 0) {
            #pragma unroll
            for (int e = 0; e < 6; ++e) lds[SCAN_OFF + e*SCAN_STR + wid] = 0.f;  // exact
        } else {
            const float* xw = xrow + segBase - (size_t)(WCH * CCH) + (size_t)wid * CCH;
            float2 t2 = *(const float2*)(xw - 2);
            v2f y1p = {0.f,0.f}, y2p = {0.f,0.f};
            float y1c = 0.f, y2c = 0.f;
            float p2 = t2.x, p1 = t2.y, dummy;
            const float4* xv = (const float4*)xw;
            float4 buf[4];
            #pragma unroll
            for (int j = 0; j < 4; ++j) buf[j] = xv[j];
            #pragma unroll
            for (int i = 0; i < 4; ++i) {
                float4 q = buf[i];
                STEP3P(q.x, p2, dummy)
                STEP3P(q.y, p1, dummy)
                STEP3P(q.z, q.x, dummy)
                STEP3P(q.w, q.y, dummy)
                p2 = q.z; p1 = q.w;
            }
            (void)dummy;
            lds[SCAN_OFF + 0*SCAN_STR + wid] = y1p.x;
            lds[SCAN_OFF + 1*SCAN_STR + wid] = y2p.x;
            lds[SCAN_OFF + 2*SCAN_STR + wid] = y1p.y;
            lds[SCAN_OFF + 3*SCAN_STR + wid] = y2p.y;
            lds[SCAN_OFF + 4*SCAN_STR + wid] = y1c;
            lds[SCAN_OFF + 5*SCAN_STR + wid] = y2c;
        }
    }
    __syncthreads();

    // -------- phase 2: block-local affine scan over 304 chunk states + H table --------
    // waves 0..2; lanes 0..47 fold 5 chunks, lanes 48..63 fold 4 (48*5+16*4=304)
    {
        const int wv = tid >> 6, ln = tid & 63;
        if (wv < 3) {
            const float A1 = na1[wv], A2 = na2[wv];
            float hm1 = 1.f, hm2 = 0.f, hm3 = 0.f;   // H(-1)=1, H(-2)=0
            for (int i = 0; i < CCH; ++i) {
                float h = fmaf(A1, hm1, A2 * hm2);
                hm3 = hm2; hm2 = hm1; hm1 = h;
                if (ln == 0) lds[H_OFF + wv * CCH + i] = h;   // H(i)
            }
            const float H00 = hm1, H01 = A2 * hm2;
            const float H10 = hm2, H11 = A2 * hm3;

            float* z1p = lds + SCAN_OFF + (2*wv) * SCAN_STR;
            float* z2p = lds + SCAN_OFF + (2*wv + 1) * SCAN_STR;

            const int cnt = (ln < 48) ? 5 : 4;
            const int beg = (ln < 48) ? 5 * ln : 240 + 4 * (ln - 48);

            float s1 = 0.f, s2 = 0.f;
            for (int j = 0; j < cnt; ++j) {
                float z1 = z1p[beg + j], z2 = z2p[beg + j];
                float n1 = z1 + H00 * s1 + H01 * s2;
                float n2 = z2 + H10 * s1 + H11 * s2;
                s1 = n1; s2 = n2;
            }
            float B00,B01,B10,B11, C00,C01,C10,C11;
            MMUL(B00,B01,B10,B11, H00,H01,H10,H11, H00,H01,H10,H11)   // H^2
            MMUL(C00,C01,C10,C11, B00,B01,B10,B11, B00,B01,B10,B11)   // H^4
            float A00 = C00, A01 = C01, A10 = C10, A11 = C11;
            if (cnt == 5) {
                float D00,D01,D10,D11;
                MMUL(D00,D01,D10,D11, C00,C01,C10,C11, H00,H01,H10,H11)
                A00 = D00; A01 = D01; A10 = D10; A11 = D11;
            }
            float bb1 = s1, bb2 = s2;
            for (int d = 1; d < 64; d <<= 1) {
                float iA00 = __shfl_up(A00, d), iA01 = __shfl_up(A01, d);
                float iA10 = __shfl_up(A10, d), iA11 = __shfl_up(A11, d);
                float ib1  = __shfl_up(bb1, d), ib2  = __shfl_up(bb2, d);
                if (ln >= d) {
                    float nb1 = A00 * ib1 + A01 * ib2 + bb1;
                    float nb2 = A10 * ib1 + A11 * ib2 + bb2;
                    float n00, n01, n10, n11;
                    MMUL(n00,n01,n10,n11, A00,A01,A10,A11, iA00,iA01,iA10,iA11)
                    A00 = n00; A01 = n01; A10 = n10; A11 = n11;
                    bb1 = nb1; bb2 = nb2;
                }
            }
            float e1 = __shfl_up(bb1, 1), e2 = __shfl_up(bb2, 1);
            if (ln == 0) { e1 = 0.f; e2 = 0.f; }

            // replay: overwrite z with corrected chunk-ENTRY states (y[-1], y[-2])
            s1 = e1; s2 = e2;
            for (int j = 0; j < cnt; ++j) {
                int w = beg + j;
                float z1 = z1p[w], z2 = z2p[w];
                z1p[w] = s1; z2p[w] = s2;
                float n1 = z1 + H00 * s1 + H01 * s2;
                float n2 = z2 + H10 * s1 + H11 * s2;
                s1 = n1; s2 = n2;
            }
        }
    }
    __syncthreads();

    // -------- phase 3: out = is3*(szs + sum_k c1k*H(t) + c2k*H(t-1)) --------
    // Sample-pair packed correction (v_pk_fma); coalesced non-temporal stores.
    {
        const float is3 = 0.57735026918962576f;   // 1/sqrt(3)
        float* obase = out + (size_t)row * S_LEN + segBase;

#define EMIT_OUT(F)                                                              \
        {                                                                        \
            const int f   = (F);                                                 \
            const int ch  = f >> 2;                                              \
            const int off = f & 3;                                               \
            const int t   = off * 4;                                             \
            const float* sp = lds + ch * OBSTR + t;                              \
            v2f o01 = {sp[0], sp[1]}, o23 = {sp[2], sp[3]};                      \
            _Pragma("unroll")                                                    \
            for (int k = 0; k < 3; ++k) {                                        \
                const float c1 = lds[SCAN_OFF + (2*k)   * SCAN_STR + WCH + ch];  \
                const float c2 = na2[k] *                                        \
                    lds[SCAN_OFF + (2*k+1) * SCAN_STR + WCH + ch];               \
                const float4 hv = *(const float4*)&lds[H_OFF + k * CCH + t];     \
                const float hm = (off == 0) ? 1.0f : lds[H_OFF + k*CCH + t - 1]; \
                v2f c1v = {c1, c1}, c2v = {c2, c2};                              \
                v2f h01 = {hv.x, hv.y}, hm01 = {hm,   hv.x};                     \
                v2f h23 = {hv.z, hv.w}, hm23 = {hv.y, hv.z};                     \
                o01 = o01 + c2v * hm01;                                          \
                o01 = o01 + c1v * h01;                                           \
                o23 = o23 + c2v * hm23;                                          \
                o23 = o23 + c1v * h23;                                           \
            }                                                                    \
            v2f sc = {is3, is3};                                                 \
            o01 = o01 * sc; o23 = o23 * sc;                                      \
            v4f o = {o01.x, o01.y, o23.x, o23.y};                                \
            __builtin_nontemporal_store(o, (v4f*)(obase + (size_t)f * 4));       \
        }

        #pragma unroll
        for (int j = 0; j < 3; ++j)
            EMIT_OUT(j * TPB + tid)
        if (tid < 1024 - 3 * TPB)              // tail: 64 float4s
            EMIT_OUT(3 * TPB + tid)
#undef EMIT_OUT
    }
}

extern "C" void kernel_launch(void* const* d_in, const int* in_sizes, int n_in,
                              void* d_out, int out_size, void* d_ws, size_t ws_size,
                              hipStream_t stream) {
    const float* audio = (const float*)d_in[0];
    const float* level = (const float*)d_in[1];
    float* out = (float*)d_out;
    (void)in_sizes; (void)n_in; (void)d_ws; (void)ws_size; (void)out_size;

    formant_onepass<<<BATCHES * SEGS, TPB, 0, stream>>>(audio, level, out);
}

// Round 18
// 56.980 us; speedup vs baseline: 1.0396x; 1.0396x over previous
//
#include <hip/hip_runtime.h>
#include <math.h>

#ifndef M_PI
#define M_PI 3.14159265358979323846
#endif

#define BATCHES 256
#define S_LEN   131072

// One kernel, independent blocks, truncated-warmup linear recurrence.
// r18: INSTRUCTION DIET. szs (zero-state band-sum, 16 floats = 4 float4) is
// held in REGISTERS across phases (feasible only at CCH=16; r10's failure was
// 64 regs at CCH=64). Phase 1: no y_zs LDS staging (16 writes removed).
// Phase 3: correction computed for the thread's OWN chunk -- c1/c2 loaded
// ONCE (6 LDS reads vs 24), H via broadcast b128 (12 reads), corrected chunk
// written as 4x ds_write_b128 (OBSTR=20, 16B aligned), then b128-read +
// nt-store emit. LDS instrs/thread ~70 -> ~26. Scan region aliases staging
// (extra barrier protects the alias); LDS 20.7KB, occupancy wave-capped at
// 6 blocks/CU (30 waves). Mechanism gate: VGPR_Count must stay <= 64.
//
// Structure (r12-r17, verified absmax 0.0039): block = 320 thr (5 waves),
// threads 0..255 own 16-sample chunks (4096-sample segment), wave 4 does 48
// warmup chunks (768 samples) concurrently; block-local affine scan (waves
// 0..2, Kogge-Stone over 304 states); homogeneous correction
// y(t)=y_zs(t)+c1*H(t)+c2*H(t-1); coalesced nt stores; __sinf coeffs.
#define TPB   320
#define MAINT 256
#define CCH   16
#define SEGS  32                      // segments per row
#define SEG_SAMPS (MAINT * CCH)       // 4096
#define WCH   48                      // warmup chunks (768 samples)
#define OBSTR 20                      // staging stride (16 samples + 4 pad; 16B-aligned b128)
#define SCAN_STR 305                  // per-array scan stride (304 + 1 pad); scan at offset 0
#define H_OFF 5120                    // H table after staging region (256*20)
#define LDSF  (H_OFF + 3 * CCH)       // 5168 floats = 20672 B -> wave-capped 6 blocks/CU

typedef float v4f __attribute__((ext_vector_type(4)));

__device__ __forceinline__ void compute_coeffs(float level_in, float b0[3], float na1[3], float na2[3]) {
    const float FD[3] = {270.0f, 800.0f, 2300.0f};
    const float FN[3] = {500.0f, 1500.0f, 2500.0f};
    const float FB[3] = {730.0f, 2100.0f, 3000.0f};
    float level = fminf(fmaxf(level_in, 0.0f), 1.0f);
    float t_low  = fminf(fmaxf(level * 2.0f, 0.0f), 1.0f);
    float t_high = fminf(fmaxf((level - 0.5f) * 2.0f, 0.0f), 1.0f);
    bool hi = (level >= 0.5f);
    const float W0 = (float)(2.0 * M_PI / 16000.0);
    #pragma unroll
    for (int k = 0; k < 3; ++k) {
        float f, q;
        if (hi) { f = (1.0f - t_high) * FN[k] + t_high * FB[k];
                  q = (1.0f - t_high) * 8.0f  + t_high * 12.0f; }
        else    { f = (1.0f - t_low) * FD[k] + t_low * FN[k];
                  q = (1.0f - t_low) * 5.0f  + t_low * 8.0f; }
        float omega = W0 * f;
        float sn = __sinf(omega), cs = __cosf(omega);   // native v_sin/v_cos
        float alpha = sn / (2.0f * fmaxf(q, 0.5f));
        float a0 = 1.0f + alpha;
        b0[k]  = alpha / a0;             // b2 == -b0 exactly
        na1[k] = (2.0f * cs) / a0;       // -a1
        na2[k] = -((1.0f - alpha) / a0); // -a2
    }
}

#define STEP3(XT, XTM2, SUMV)                                                    \
    {                                                                            \
        float d = (XT) - (XTM2);                                                 \
        float e0 = fmaf(b0[0], d, na2[0] * y2[0]);                               \
        float e1 = fmaf(b0[1], d, na2[1] * y2[1]);                               \
        float e2 = fmaf(b0[2], d, na2[2] * y2[2]);                               \
        float yy0 = fmaf(na1[0], y1[0], e0);                                     \
        float yy1 = fmaf(na1[1], y1[1], e1);                                     \
        float yy2 = fmaf(na1[2], y1[2], e2);                                     \
        y2[0] = y1[0]; y1[0] = yy0;                                              \
        y2[1] = y1[1]; y1[1] = yy1;                                              \
        y2[2] = y1[2]; y1[2] = yy2;                                              \
        SUMV = (yy0 + yy1 + yy2);                                                \
    }

// 2x2 matrix multiply: R = X * Y
#define MMUL(R00,R01,R10,R11, X00,X01,X10,X11, Y00,Y01,Y10,Y11)                  \
    {                                                                            \
        R00 = X00*Y00 + X01*Y10; R01 = X00*Y01 + X01*Y11;                        \
        R10 = X10*Y00 + X11*Y10; R11 = X10*Y01 + X11*Y11;                        \
    }

__global__ __launch_bounds__(TPB, 2)
void formant_onepass(const float* __restrict__ x, const float* __restrict__ lvl,
                     float* __restrict__ out)
{
    __shared__ float lds[LDSF];

    const int tid = threadIdx.x;
    const int row = blockIdx.x >> 5;
    const int seg = blockIdx.x & (SEGS - 1);

    float b0[3], na1[3], na2[3];
    compute_coeffs(lvl[row], b0, na1, na2);

    const float* xrow = x + (size_t)row * S_LEN;
    const size_t segBase = (size_t)seg * SEG_SAMPS;

    float4 szs[4];   // zero-state band-sum, 16 VGPR, live P1 -> P3b

    // -------- phase 1a: main-chunk zero-state, szs kept in registers --------
    if (tid < MAINT) {
        const float* xc = xrow + segBase + (size_t)tid * CCH;
        float xm1 = 0.f, xm2 = 0.f;
        if (seg > 0 || tid > 0) { float2 t2 = *(const float2*)(xc - 2); xm2 = t2.x; xm1 = t2.y; }
        float y1[3] = {0.f,0.f,0.f}, y2[3] = {0.f,0.f,0.f};
        const float4* xv = (const float4*)xc;
        float4 buf[4];
        #pragma unroll
        for (int j = 0; j < 4; ++j) buf[j] = xv[j];
        #pragma unroll
        for (int i = 0; i < 4; ++i) {
            float4 q = buf[i];
            float4 o;
            STEP3(q.x, xm2, o.x)
            STEP3(q.y, xm1, o.y)
            STEP3(q.z, q.x, o.z)
            STEP3(q.w, q.y, o.w)
            xm2 = q.z; xm1 = q.w;
            szs[i] = o;
        }
        // end-of-chunk states -> scan arrays (offset 0) at index WCH+tid
        lds[0*SCAN_STR + WCH + tid] = y1[0];
        lds[1*SCAN_STR + WCH + tid] = y2[0];
        lds[2*SCAN_STR + WCH + tid] = y1[1];
        lds[3*SCAN_STR + WCH + tid] = y2[1];
        lds[4*SCAN_STR + WCH + tid] = y1[2];
        lds[5*SCAN_STR + WCH + tid] = y2[2];
    }
    // -------- phase 1b: warmup chunks on DEDICATED wave 4 (threads 256..303) --------
    else if (tid < MAINT + WCH) {
        const int wid = tid - MAINT;
        if (seg == 0) {
            #pragma unroll
            for (int e = 0; e < 6; ++e) lds[e*SCAN_STR + wid] = 0.f;   // exact
        } else {
            const float* xw = xrow + segBase - (size_t)(WCH * CCH) + (size_t)wid * CCH;
            float2 t2 = *(const float2*)(xw - 2);
            float y1[3] = {0.f,0.f,0.f}, y2[3] = {0.f,0.f,0.f};
            float p2 = t2.x, p1 = t2.y, dummy;
            const float4* xv = (const float4*)xw;
            float4 buf[4];
            #pragma unroll
            for (int j = 0; j < 4; ++j) buf[j] = xv[j];
            #pragma unroll
            for (int i = 0; i < 4; ++i) {
                float4 q = buf[i];
                STEP3(q.x, p2, dummy)
                STEP3(q.y, p1, dummy)
                STEP3(q.z, q.x, dummy)
                STEP3(q.w, q.y, dummy)
                p2 = q.z; p1 = q.w;
            }
            (void)dummy;
            lds[0*SCAN_STR + wid] = y1[0];
            lds[1*SCAN_STR + wid] = y2[0];
            lds[2*SCAN_STR + wid] = y1[1];
            lds[3*SCAN_STR + wid] = y2[1];
            lds[4*SCAN_STR + wid] = y1[2];
            lds[5*SCAN_STR + wid] = y2[2];
        }
    }
    __syncthreads();

    // -------- phase 2: block-local affine scan over 304 chunk states + H table --------
    // waves 0..2; lanes 0..47 fold 5 chunks, lanes 48..63 fold 4 (48*5+16*4=304)
    {
        const int wv = tid >> 6, ln = tid & 63;
        if (wv < 3) {
            const float A1 = na1[wv], A2 = na2[wv];
            float hm1 = 1.f, hm2 = 0.f, hm3 = 0.f;   // H(-1)=1, H(-2)=0
            for (int i = 0; i < CCH; ++i) {
                float h = fmaf(A1, hm1, A2 * hm2);
                hm3 = hm2; hm2 = hm1; hm1 = h;
                if (ln == 0) lds[H_OFF + wv * CCH + i] = h;   // H(i)
            }
            const float H00 = hm1, H01 = A2 * hm2;
            const float H10 = hm2, H11 = A2 * hm3;

            float* z1p = lds + (2*wv) * SCAN_STR;
            float* z2p = lds + (2*wv + 1) * SCAN_STR;

            const int cnt = (ln < 48) ? 5 : 4;
            const int beg = (ln < 48) ? 5 * ln : 240 + 4 * (ln - 48);

            float s1 = 0.f, s2 = 0.f;
            for (int j = 0; j < cnt; ++j) {
                float z1 = z1p[beg + j], z2 = z2p[beg + j];
                float n1 = z1 + H00 * s1 + H01 * s2;
                float n2 = z2 + H10 * s1 + H11 * s2;
                s1 = n1; s2 = n2;
            }
            float B00,B01,B10,B11, C00,C01,C10,C11;
            MMUL(B00,B01,B10,B11, H00,H01,H10,H11, H00,H01,H10,H11)   // H^2
            MMUL(C00,C01,C10,C11, B00,B01,B10,B11, B00,B01,B10,B11)   // H^4
            float A00 = C00, A01 = C01, A10 = C10, A11 = C11;
            if (cnt == 5) {
                float D00,D01,D10,D11;
                MMUL(D00,D01,D10,D11, C00,C01,C10,C11, H00,H01,H10,H11)
                A00 = D00; A01 = D01; A10 = D10; A11 = D11;
            }
            float bb1 = s1, bb2 = s2;
            for (int d = 1; d < 64; d <<= 1) {
                float iA00 = __shfl_up(A00, d), iA01 = __shfl_up(A01, d);
                float iA10 = __shfl_up(A10, d), iA11 = __shfl_up(A11, d);
                float ib1  = __shfl_up(bb1, d), ib2  = __shfl_up(bb2, d);
                if (ln >= d) {
                    float nb1 = A00 * ib1 + A01 * ib2 + bb1;
                    float nb2 = A10 * ib1 + A11 * ib2 + bb2;
                    float n00, n01, n10, n11;
                    MMUL(n00,n01,n10,n11, A00,A01,A10,A11, iA00,iA01,iA10,iA11)
                    A00 = n00; A01 = n01; A10 = n10; A11 = n11;
                    bb1 = nb1; bb2 = nb2;
                }
            }
            float e1 = __shfl_up(bb1, 1), e2 = __shfl_up(bb2, 1);
            if (ln == 0) { e1 = 0.f; e2 = 0.f; }

            // replay: overwrite z with corrected chunk-ENTRY states (y[-1], y[-2])
            s1 = e1; s2 = e2;
            for (int j = 0; j < cnt; ++j) {
                int w = beg + j;
                float z1 = z1p[w], z2 = z2p[w];
                z1p[w] = s1; z2p[w] = s2;
                float n1 = z1 + H00 * s1 + H01 * s2;
                float n2 = z2 + H10 * s1 + H11 * s2;
                s1 = n1; s2 = n2;
            }
        }
    }
    __syncthreads();

    // -------- phase 3a: load correction coeffs ONCE (before staging aliases scan) ----
    float c1k[3], c2k[3];
    if (tid < MAINT) {
        #pragma unroll
        for (int k = 0; k < 3; ++k) {
            c1k[k] = lds[(2*k) * SCAN_STR + WCH + tid];
            c2k[k] = na2[k] * lds[(2*k + 1) * SCAN_STR + WCH + tid];
        }
    }
    __syncthreads();   // all c-reads done; staging may now overwrite scan region

    // -------- phase 3b: correct OWN chunk in registers; b128 store to staging ----
    if (tid < MAINT) {
        const float is3 = 0.57735026918962576f;   // 1/sqrt(3)
        float* myst = lds + tid * OBSTR;
        float hp[3] = {1.f, 1.f, 1.f};            // H(-1) = 1
        #pragma unroll
        for (int i = 0; i < 4; ++i) {
            float4 s = szs[i];
            float o0 = s.x, o1 = s.y, o2 = s.z, o3 = s.w;
            #pragma unroll
            for (int k = 0; k < 3; ++k) {
                const float4 hv = *(const float4*)&lds[H_OFF + k * CCH + 4 * i]; // broadcast
                o0 = fmaf(c1k[k], hv.x, fmaf(c2k[k], hp[k], o0));
                o1 = fmaf(c1k[k], hv.y, fmaf(c2k[k], hv.x,  o1));
                o2 = fmaf(c1k[k], hv.z, fmaf(c2k[k], hv.y,  o2));
                o3 = fmaf(c1k[k], hv.w, fmaf(c2k[k], hv.z,  o3));
                hp[k] = hv.w;
            }
            v4f o = { o0 * is3, o1 * is3, o2 * is3, o3 * is3 };
            *(v4f*)(myst + 4 * i) = o;            // ds_write_b128, 16B aligned
        }
    }
    __syncthreads();

    // -------- phase 3c: coalesced nt store (1024 float4 over 320 threads) --------
    {
        float* obase = out + (size_t)row * S_LEN + segBase;
        #pragma unroll
        for (int j = 0; j < 3; ++j) {
            const int f = j * TPB + tid;
            const v4f o = *(const v4f*)(lds + (f >> 2) * OBSTR + (f & 3) * 4);
            __builtin_nontemporal_store(o, (v4f*)(obase + (size_t)f * 4));
        }
        if (tid < 1024 - 3 * TPB) {               // tail: 64 float4s
            const int f = 3 * TPB + tid;
            const v4f o = *(const v4f*)(lds + (f >> 2) * OBSTR + (f & 3) * 4);
            __builtin_nontemporal_store(o, (v4f*)(obase + (size_t)f * 4));
        }
    }
}

extern "C" void kernel_launch(void* const* d_in, const int* in_sizes, int n_in,
                              void* d_out, int out_size, void* d_ws, size_t ws_size,
                              hipStream_t stream) {
    const float* audio = (const float*)d_in[0];
    const float* level = (const float*)d_in[1];
    float* out = (float*)d_out;
    (void)in_sizes; (void)n_in; (void)d_ws; (void)ws_size; (void)out_size;

    formant_onepass<<<BATCHES * SEGS, TPB, 0, stream>>>(audio, level, out);
}